// Round 8
// baseline (55.594 us; speedup 1.0000x reference)
//
#include <hip/hip_runtime.h>

// WaveletFeatures: pywt.wavedec(x, 'db4', level=3, mode='symmetric') per row.
// out = concat([cA3, cD3, cD2, cD1]), each [B, Mk] row-major, flat fp32.
// y[m] = sum_{s=0..7} f[s] * x_sym[2m+1-s];  sym: o<0 -> -1-o ; o>=n -> 2n-1-o.
//
// R8 = R7 segmented cascade (half-row per block, 8192 blocks) +
//  (a) x staged to LDS in ONE perfectly-coalesced float4 pass (each input
//      element read exactly once, 16B lane stride; kills the 2x window
//      overlap / split-sector reads of R2..R7), and
//  (b) phase-aligned nontemporal float4 stores for cD1/cD2/cA3/cD3 (R6
//      machinery adapted to segment seams; odd row lengths give per-row
//      alignment phases ph1=r%4, ph2=-r%4, ph3=2r%4).
// LDS views are GLOBAL-INDEXED pointers (sxg/s1g/s2g = buf - seg_offset,
// offsets 4-aligned so LDS slot mod 4 == global index mod 4 -> all
// ds_read_b128 16B-aligned). cA LDS writes are scalar (phase-misaligned).
// Chunk windows read 2 garbage floats below the staged span in 2 places
// (w[0..1] unused by the math; slots are in-buffer pad).

constexpr int N0 = 8192;
constexpr int M1 = 4099;  // floor((8192+7)/2)
constexpr int M2 = 2053;
constexpr int M3 = 1030;
constexpr int NT = 256;

typedef float vfloat4 __attribute__((ext_vector_type(4)));

__device__ __forceinline__ int symidx(int o, int n) {
    if (o < 0) o = -1 - o;
    if (o >= n) o = 2 * n - 1 - o;  // single reflection (overhang <= 6)
    return o;
}

// 4 output pairs; uses w[2..15] only: y[i0+j] = sum_t RF[t] * w[2j+2+t]
__device__ __forceinline__ void compute4(const float* __restrict__ w,
                                         float* __restrict__ a,
                                         float* __restrict__ d) {
    constexpr float RLO[8] = {0.23037781330885523f,  0.7148465705525415f,
                              0.6308807679295904f,   -0.02798376941698385f,
                              -0.18703481171888114f, 0.030841381835986965f,
                              0.032883011666982945f, -0.010597401784997278f};
    constexpr float RHI[8] = {-0.010597401784997278f, -0.032883011666982945f,
                              0.030841381835986965f,  0.18703481171888114f,
                              -0.02798376941698385f,  -0.6308807679295904f,
                              0.7148465705525415f,    -0.23037781330885523f};
#pragma unroll
    for (int j = 0; j < 4; ++j) {
        float aj = 0.f, dj = 0.f;
#pragma unroll
        for (int t = 0; t < 8; ++t) {
            const float v = w[2 * j + 2 + t];
            aj = fmaf(RLO[t], v, aj);
            dj = fmaf(RHI[t], v, dj);
        }
        a[j] = aj;
        d[j] = dj;
    }
}

// in = GLOBAL-INDEXED pointer (LDS view); reads 16(+4) floats from
// in + 2*i0 - 8 - PAD (16B-aligned given i0 phase parity matches PAD).
template <int PAD>
__device__ __forceinline__ void chunk(const float* __restrict__ in, int i0,
                                      float* __restrict__ a,
                                      float* __restrict__ d) {
    float w[16 + (PAD ? 4 : 0)];
    const float* p = in + 2 * i0 - 8 - PAD;
    *reinterpret_cast<float4*>(&w[0]) = *reinterpret_cast<const float4*>(p);
    *reinterpret_cast<float4*>(&w[4]) = *reinterpret_cast<const float4*>(p + 4);
    *reinterpret_cast<float4*>(&w[8]) = *reinterpret_cast<const float4*>(p + 8);
    *reinterpret_cast<float4*>(&w[12]) =
        *reinterpret_cast<const float4*>(p + 12);
    if constexpr (PAD != 0)
        *reinterpret_cast<float4*>(&w[16]) =
            *reinterpret_cast<const float4*>(p + 16);
    compute4(w + PAD, a, d);
}

__device__ __forceinline__ void edge_pair(const float* in, int n, int i,
                                          float& a, float& d) {
    constexpr float LO[8] = {
        -0.010597401784997278f, 0.032883011666982945f, 0.030841381835986965f,
        -0.18703481171888114f,  -0.02798376941698385f, 0.6308807679295904f,
        0.7148465705525415f,    0.23037781330885523f};
    constexpr float HI[8] = {
        -0.23037781330885523f,  0.7148465705525415f,   -0.6308807679295904f,
        -0.02798376941698385f,  0.18703481171888114f,  0.030841381835986965f,
        -0.032883011666982945f, -0.010597401784997278f};
    a = 0.f;
    d = 0.f;
#pragma unroll
    for (int s = 0; s < 8; ++s) {
        const float v = in[symidx(2 * i + 1 - s, n)];
        a = fmaf(LO[s], v, a);
        d = fmaf(HI[s], v, d);
    }
}

__device__ __forceinline__ void ntst4(float* dst, const float* v) {
    vfloat4 t = {v[0], v[1], v[2], v[3]};
    __builtin_nontemporal_store(t, reinterpret_cast<vfloat4*>(dst));
}

__global__ __launch_bounds__(NT) void WaveletFeatures_77214922047612_kernel(
    const float* __restrict__ x, float* __restrict__ out, int B) {
    __shared__ __align__(16) float sx[4132];  // x segment
    __shared__ __align__(16) float s1[2068];  // cA1 segment
    __shared__ __align__(16) float s2[1036];  // cA2 segment

    const int bid = blockIdx.x;
    const int row = bid >> 1;
    const int seg = bid & 1;
    const int tid = threadIdx.x;
    const int r4 = row & 3;
    const float* xr = x + (size_t)row * N0;

    float* ca3 = out + (size_t)row * M3;
    float* cd3 = out + (size_t)B * M3 + (size_t)row * M3;
    float* cd2 = out + 2 * (size_t)B * M3 + (size_t)row * M2;
    float* cd1 = out + (size_t)B * (2 * M3 + M2) + (size_t)row * M1;

    const int ph1 = r4;             // cd1[i] 16B-aligned iff i==ph1 (mod 4)
    const int ph2 = (4 - r4) & 3;   // cd2
    const int ph3 = (2 * r4) & 3;   // ca3/cd3 (always even)

    // global-indexed LDS views (offsets 4-aligned: slot%4 == global_idx%4)
    const int xlo = seg ? 4084 : 0;
    float* const sxg = sx - xlo;
    float* const s1g = s1 - (seg ? 2044 : 0);
    float* const s2g = s2 - (seg ? 1024 : 0);

    // ---- stage x segment, perfectly coalesced, each element once ---------
    {
        const int nx4 = seg ? 1027 : 1032;  // seg0 g:[0,4128) seg1 g:[4084,8192)
        const float4* src = reinterpret_cast<const float4*>(xr + xlo);
        float4* dst = reinterpret_cast<float4*>(sx);
        for (int k = tid; k < nx4; k += NT) dst[k] = src[k];
    }
    __syncthreads();

    // ---- P1: sxg (n=8192) -> cA1 in s1g, own cD1 -> global (nt f4) -------
    {
        int clo, chi, sl0, sr1, own0, own1;
        if (seg) {
            clo = 2052 + ph1;
            chi = (ph1 == 0) ? 4092 : (ph1 == 1) ? 4089 : (ph1 == 2) ? 4090 : 4091;
            sl0 = 2046; sr1 = 4099; own0 = 2052; own1 = 4099;
        } else {
            clo = ph1 + 4;
            chi = (ph1 == 0) ? 2048 : 2044 + ph1;
            sl0 = 0; sr1 = 2064; own0 = 0; own1 = 2052;
        }
        const int C = (chi - clo) / 4 + 1;
        if (ph1 & 1) {
            for (int c = tid; c < C; c += NT) {
                const int i0 = clo + 4 * c;
                float a[4], d[4];
                chunk<2>(sxg, i0, a, d);
                s1g[i0] = a[0]; s1g[i0 + 1] = a[1];
                s1g[i0 + 2] = a[2]; s1g[i0 + 3] = a[3];
                ntst4(&cd1[i0], d);
            }
        } else {
            for (int c = tid; c < C; c += NT) {
                const int i0 = clo + 4 * c;
                float a[4], d[4];
                chunk<0>(sxg, i0, a, d);
                s1g[i0] = a[0]; s1g[i0 + 1] = a[1];
                s1g[i0 + 2] = a[2]; s1g[i0 + 3] = a[3];
                ntst4(&cd1[i0], d);
            }
        }
        const int nl = clo - sl0, nr = sr1 - (chi + 4);
        if (tid < nl + nr) {
            const int i = tid < nl ? sl0 + tid : chi + 4 + (tid - nl);
            float a, d;
            edge_pair(sxg, N0, i, a, d);
            s1g[i] = a;
            if (i >= own0 && i < own1) cd1[i] = d;
        }
    }
    __syncthreads();

    // ---- P2: s1g (n=4099) -> cA2 in s2g, own cD2 -> global (nt f4) -------
    {
        int clo, chi, sl0, sr1, own0, own1;
        if (seg) {
            clo = 1028 + ph2;
            chi = (ph2 == 0) ? 2044 : 2040 + ph2;
            sl0 = 1026; sr1 = 2053; own0 = 1028; own1 = 2053;
        } else {
            clo = ph2 + 4;
            chi = (ph2 == 0) ? 1024 : 1020 + ph2;
            sl0 = 0; sr1 = 1032; own0 = 0; own1 = 1028;
        }
        const int C = (chi - clo) / 4 + 1;
        if (ph2 & 1) {
            for (int c = tid; c < C; c += NT) {
                const int i0 = clo + 4 * c;
                float a[4], d[4];
                chunk<2>(s1g, i0, a, d);
                s2g[i0] = a[0]; s2g[i0 + 1] = a[1];
                s2g[i0 + 2] = a[2]; s2g[i0 + 3] = a[3];
                ntst4(&cd2[i0], d);
            }
        } else {
            for (int c = tid; c < C; c += NT) {
                const int i0 = clo + 4 * c;
                float a[4], d[4];
                chunk<0>(s1g, i0, a, d);
                s2g[i0] = a[0]; s2g[i0 + 1] = a[1];
                s2g[i0 + 2] = a[2]; s2g[i0 + 3] = a[3];
                ntst4(&cd2[i0], d);
            }
        }
        const int nl = clo - sl0, nr = sr1 - (chi + 4);
        if (tid < nl + nr) {
            const int i = tid < nl ? sl0 + tid : chi + 4 + (tid - nl);
            float a, d;
            edge_pair(s1g, M1, i, a, d);
            s2g[i] = a;
            if (i >= own0 && i < own1) cd2[i] = d;
        }
    }
    __syncthreads();

    // ---- P3: s2g (n=2053) -> own cA3/cD3 -> global (nt f4) ---------------
    {
        int clo, chi, sl0, sr1;
        if (seg) {
            clo = 516 + ph3;                  // ph3 in {0,2}
            chi = (ph3 == 0) ? 1020 : 1018;
            sl0 = 516; sr1 = 1030;
        } else {
            clo = ph3 + 4;
            chi = (ph3 == 0) ? 512 : 510;
            sl0 = 0; sr1 = 516;
        }
        const int C = (chi - clo) / 4 + 1;
        for (int c = tid; c < C; c += NT) {
            const int i0 = clo + 4 * c;
            float a[4], d[4];
            chunk<0>(s2g, i0, a, d);
            ntst4(&ca3[i0], a);
            ntst4(&cd3[i0], d);
        }
        const int nl = clo - sl0, nr = sr1 - (chi + 4);
        if (tid < nl + nr) {
            const int i = tid < nl ? sl0 + tid : chi + 4 + (tid - nl);
            float a, d;
            edge_pair(s2g, M2, i, a, d);
            ca3[i] = a;
            cd3[i] = d;
        }
    }
}

extern "C" void kernel_launch(void* const* d_in, const int* in_sizes, int n_in,
                              void* d_out, int out_size, void* d_ws,
                              size_t ws_size, hipStream_t stream) {
    const float* x = (const float*)d_in[0];
    float* out = (float*)d_out;
    const int B = in_sizes[0] / N0;  // 4096
    WaveletFeatures_77214922047612_kernel<<<dim3(2 * B), dim3(NT), 0, stream>>>(
        x, out, B);
}

// Round 9
// 47.537 us; speedup vs baseline: 1.1695x; 1.1695x over previous
//
#include <hip/hip_runtime.h>

// WaveletFeatures: pywt.wavedec(x, 'db4', level=3, mode='symmetric') per row.
// out = concat([cA3, cD3, cD2, cD1]), each [B, Mk] row-major, flat fp32.
// y[m] = sum_{s=0..7} f[s] * x_sym[2m+1-s];  sym: o<0 -> -1-o ; o>=n -> 2n-1-o.
//
// FINAL (= R7, session best 47.1us): segmented cascade. Each block does HALF
// a row through all 3 levels (level-3 split [0,516)/[516,1030) propagated
// down with conv halos). LDS 12.4KB -> 8 blocks/CU, 8192 blocks. Seam values
// computed from in-span halo (extras, cA-only); true edges via symidx. LDS
// vector ops 16B-aligned via global-indexed offset pointers.
//
// Roofline note (R2/R6/R7/R8 arc): logical traffic floor = 269MB (read input
// once + write output once, both irreducible); measured 47.1us = 5.71 TB/s =
// 91% of the 6.29 TB/s device copy ceiling. Three structurally distinct
// kernels (occupancy 53-67%, scalar vs nt-vector stores, 4096 vs 8192
// blocks, ~2x VMEM count spread) all plateau at 47us with FETCH pinned at
// 66MB (input minus L3-resident half) and WRITE at exactly output size —
// fabric-rate-bound, not kernel-structure-bound.

constexpr int N0 = 8192;
constexpr int M1 = 4099;  // floor((8192+7)/2)
constexpr int M2 = 2053;
constexpr int M3 = 1030;
constexpr int NT = 256;

__device__ __forceinline__ int symidx(int o, int n) {
    if (o < 0) o = -1 - o;
    if (o >= n) o = 2 * n - 1 - o;  // single reflection (overhang <= 6)
    return o;
}

// 4 output pairs from w[k] = in[2*i0 - 8 + k]: y[i0+j] = sum_t RF[t]*w[2j+2+t]
// (w[0], w[1] are unused by the math; they may hold garbage halo slots.)
__device__ __forceinline__ void compute4(const float* __restrict__ w,
                                         float* __restrict__ a,
                                         float* __restrict__ d) {
    constexpr float RLO[8] = {0.23037781330885523f,  0.7148465705525415f,
                              0.6308807679295904f,   -0.02798376941698385f,
                              -0.18703481171888114f, 0.030841381835986965f,
                              0.032883011666982945f, -0.010597401784997278f};
    constexpr float RHI[8] = {-0.010597401784997278f, -0.032883011666982945f,
                              0.030841381835986965f,  0.18703481171888114f,
                              -0.02798376941698385f,  -0.6308807679295904f,
                              0.7148465705525415f,    -0.23037781330885523f};
#pragma unroll
    for (int j = 0; j < 4; ++j) {
        float aj = 0.f, dj = 0.f;
#pragma unroll
        for (int t = 0; t < 8; ++t) {
            const float v = w[2 * j + 2 + t];
            aj = fmaf(RLO[t], v, aj);
            dj = fmaf(RHI[t], v, dj);
        }
        a[j] = aj;
        d[j] = dj;
    }
}

__device__ __forceinline__ void load16(const float* __restrict__ p,
                                       float* __restrict__ w) {
    *reinterpret_cast<float4*>(&w[0]) = *reinterpret_cast<const float4*>(p);
    *reinterpret_cast<float4*>(&w[4]) = *reinterpret_cast<const float4*>(p + 4);
    *reinterpret_cast<float4*>(&w[8]) = *reinterpret_cast<const float4*>(p + 8);
    *reinterpret_cast<float4*>(&w[12]) =
        *reinterpret_cast<const float4*>(p + 12);
}

__device__ __forceinline__ void edge_pair(const float* in, int n, int i,
                                          float& a, float& d) {
    constexpr float LO[8] = {
        -0.010597401784997278f, 0.032883011666982945f, 0.030841381835986965f,
        -0.18703481171888114f,  -0.02798376941698385f, 0.6308807679295904f,
        0.7148465705525415f,    0.23037781330885523f};
    constexpr float HI[8] = {
        -0.23037781330885523f,  0.7148465705525415f,   -0.6308807679295904f,
        -0.02798376941698385f,  0.18703481171888114f,  0.030841381835986965f,
        -0.032883011666982945f, -0.010597401784997278f};
    a = 0.f;
    d = 0.f;
#pragma unroll
    for (int s = 0; s < 8; ++s) {
        const float v = in[symidx(2 * i + 1 - s, n)];
        a = fmaf(LO[s], v, a);
        d = fmaf(HI[s], v, d);
    }
}

__global__ __launch_bounds__(NT) void WaveletFeatures_77214922047612_kernel(
    const float* __restrict__ x, float* __restrict__ out, int B) {
    __shared__ __align__(16) float s1buf[2068];  // cA1 segment (+pad)
    __shared__ __align__(16) float s2buf[1036];  // cA2 segment (+pad)

    const int bid = blockIdx.x;
    const int row = bid >> 1;
    const int seg = bid & 1;
    const int tid = threadIdx.x;
    const float* xr = x + (size_t)row * N0;

    float* ca3 = out + (size_t)row * M3;
    float* cd3 = out + (size_t)B * M3 + (size_t)row * M3;
    float* cd2 = out + 2 * (size_t)B * M3 + (size_t)row * M2;
    float* cd1 = out + (size_t)B * (2 * M3 + M2) + (size_t)row * M1;

    const int lo1 = seg ? 2046 : 0;
    const int lo2 = seg ? 1026 : 0;
    // global-index addressing into the LDS segments; pad keeps 16B alignment
    float* const s1g = s1buf + (lo1 & 3) - lo1;
    float* const s2g = s2buf + (lo2 & 3) - lo2;

    // ---- P1: x (global, n=8192) -> cA1 seg in s1g, owned cD1 -> global ----
    {
        const int allo = seg ? 2052 : 4;
        const int C = seg ? 511 : 512;
        for (int c = tid; c < C; c += NT) {
            const int i0 = allo + 4 * c;
            float w[16];
            load16(xr + 2 * i0 - 8, w);
            float a[4], d[4];
            compute4(w, a, d);
            *reinterpret_cast<float4*>(&s1g[i0]) =
                make_float4(a[0], a[1], a[2], a[3]);
            cd1[i0] = d[0]; cd1[i0 + 1] = d[1];
            cd1[i0 + 2] = d[2]; cd1[i0 + 3] = d[3];
        }
        const int nl = seg ? 0 : 4;   // left true-edge, both outputs
        const int nr = seg ? 3 : 0;   // right true-edge [4096,4099)
        const int ne = seg ? 6 : 12;  // halo extras, cA-only
        const int exlo = seg ? 2046 : 2052;
        if (tid < nl + nr + ne) {
            int i;
            bool both;
            if (tid < nl) { i = tid; both = true; }
            else if (tid < nl + nr) { i = 4096 + tid - nl; both = true; }
            else { i = exlo + tid - nl - nr; both = false; }
            float a, d;
            edge_pair(xr, N0, i, a, d);
            s1g[i] = a;
            if (both) cd1[i] = d;
        }
    }
    __syncthreads();

    // ---- P2: s1g (n=4099) -> cA2 seg in s2g, owned cD2 -> global ----------
    {
        const int allo = seg ? 1028 : 4;
        const int C = seg ? 255 : 256;
        for (int c = tid; c < C; c += NT) {
            const int i0 = allo + 4 * c;
            float w[16];
            load16(s1g + 2 * i0 - 8, w);
            float a[4], d[4];
            compute4(w, a, d);
            *reinterpret_cast<float4*>(&s2g[i0]) =
                make_float4(a[0], a[1], a[2], a[3]);
            cd2[i0] = d[0]; cd2[i0 + 1] = d[1];
            cd2[i0 + 2] = d[2]; cd2[i0 + 3] = d[3];
        }
        const int nl = seg ? 0 : 4;
        const int nr = seg ? 5 : 0;  // [2048,2053) true right edge
        const int ne = seg ? 2 : 4;
        const int exlo = seg ? 1026 : 1028;
        if (tid < nl + nr + ne) {
            int i;
            bool both;
            if (tid < nl) { i = tid; both = true; }
            else if (tid < nl + nr) { i = 2048 + tid - nl; both = true; }
            else { i = exlo + tid - nl - nr; both = false; }
            float a, d;
            edge_pair(s1g, M1, i, a, d);
            s2g[i] = a;
            if (both) cd2[i] = d;
        }
    }
    __syncthreads();

    // ---- P3: s2g (n=2053) -> owned cA3/cD3 -> global ----------------------
    {
        const int allo = seg ? 516 : 4;
        const int C = 127;
        for (int c = tid; c < C; c += NT) {
            const int i0 = allo + 4 * c;
            float w[16];
            load16(s2g + 2 * i0 - 8, w);
            float a[4], d[4];
            compute4(w, a, d);
#pragma unroll
            for (int j = 0; j < 4; ++j) {
                ca3[i0 + j] = a[j];
                cd3[i0 + j] = d[j];
            }
        }
        const int nl = seg ? 0 : 4;  // [0,4)
        const int nr = seg ? 6 : 4;  // seg0: [512,516); seg1: [1024,1030)
        const int alhi = seg ? 1024 : 512;
        if (tid < nl + nr) {
            const int i = tid < nl ? tid : alhi + tid - nl;
            float a, d;
            edge_pair(s2g, M2, i, a, d);
            ca3[i] = a;
            cd3[i] = d;
        }
    }
}

extern "C" void kernel_launch(void* const* d_in, const int* in_sizes, int n_in,
                              void* d_out, int out_size, void* d_ws,
                              size_t ws_size, hipStream_t stream) {
    const float* x = (const float*)d_in[0];
    float* out = (float*)d_out;
    const int B = in_sizes[0] / N0;  // 4096
    WaveletFeatures_77214922047612_kernel<<<dim3(2 * B), dim3(NT), 0, stream>>>(
        x, out, B);
}